// Round 1
// baseline (13695.395 us; speedup 1.0000x reference)
//
#include <hip/hip_runtime.h>
#include <hip/hip_bf16.h>

#define B_ 128
#define T_ 1024
#define I_ 512
#define H_ 1024
#define O_ 512
#define KC 1536  // H_ + I_

typedef __attribute__((ext_vector_type(8))) short bf16x8;
typedef __attribute__((ext_vector_type(4))) float f32x4;
typedef unsigned short ushort_t;

__device__ __forceinline__ unsigned f2bf_u(float f) {
  union { float f; unsigned u; } v; v.f = f;
  return (v.u + 0x7fffu + ((v.u >> 16) & 1u)) >> 16;  // RNE bf16
}

__device__ __forceinline__ ushort_t f2bf(float f) { return (ushort_t)f2bf_u(f); }

// load 8 contiguous fp32 and pack to bf16x8 (for A-fragments sourced from fp32 x)
__device__ __forceinline__ bf16x8 cvt8(const float* __restrict__ p) {
  union { bf16x8 v; unsigned u[4]; } r;
  const float4 f0 = *(const float4*)p;
  const float4 f1 = *(const float4*)(p + 4);
  r.u[0] = f2bf_u(f0.x) | (f2bf_u(f0.y) << 16);
  r.u[1] = f2bf_u(f0.z) | (f2bf_u(f0.w) << 16);
  r.u[2] = f2bf_u(f1.x) | (f2bf_u(f1.y) << 16);
  r.u[3] = f2bf_u(f1.z) | (f2bf_u(f1.w) << 16);
  return r.v;
}

// Build Wcat = [W_hh | W_ih] (H_ rows x KC cols, bf16), W_ho bf16, bcat = b_ih + b_hh, zero h0.
__global__ void k_prep(const float* __restrict__ Whh, const float* __restrict__ Wih,
                       const float* __restrict__ Who, const float* __restrict__ bih,
                       const float* __restrict__ bhh,
                       ushort_t* __restrict__ Wcat, ushort_t* __restrict__ Wob,
                       float* __restrict__ bcat, ushort_t* __restrict__ h0) {
  int idx = blockIdx.x * 256 + threadIdx.x;
  int nthr = gridDim.x * 256;
  for (int i = idx; i < H_ * KC; i += nthr) {
    int n = i / KC, k = i - n * KC;
    float v = (k < H_) ? Whh[n * H_ + k] : Wih[n * I_ + (k - H_)];
    Wcat[i] = f2bf(v);
  }
  for (int i = idx; i < O_ * H_; i += nthr) Wob[i] = f2bf(Who[i]);
  for (int i = idx; i < H_; i += nthr) bcat[i] = bih[i] + bhh[i];
  for (int i = idx; i < B_ * H_; i += nthr) h0[i] = 0;
}

// One recurrence step: h_nxt = relu([h_cur | x_t] @ Wcat^T + bcat)
// grid = 256 blocks x 64 threads; block computes a 32(row=batch) x 16(col=hidden) tile.
__global__ __launch_bounds__(64) void k_step(const ushort_t* __restrict__ h_cur,
                                             ushort_t* __restrict__ h_nxt,
                                             const float* __restrict__ x,
                                             const ushort_t* __restrict__ Wcat,
                                             const float* __restrict__ bcat, int t) {
  const int lane = threadIdx.x;
  const int lr = lane & 15;   // fragment row/col index
  const int kg = lane >> 4;   // k-group: k0 = kg*8
  const int bm = blockIdx.x & 3;     // 4 row tiles of 32
  const int bn = blockIdx.x >> 2;    // 64 col tiles of 16
  const int r0 = bm * 32, c0 = bn * 16;

  const ushort_t* pa0 = h_cur + (r0 + lr) * H_ + kg * 8;
  const ushort_t* pa1 = pa0 + 16 * H_;
  const ushort_t* pb  = Wcat + (c0 + lr) * KC + kg * 8;

  f32x4 acc0 = {0.f, 0.f, 0.f, 0.f};
  f32x4 acc1 = {0.f, 0.f, 0.f, 0.f};

  // K-part 1: recurrent h @ W_hh^T  (K = 1024, bf16 source)
  #pragma unroll 4
  for (int k0 = 0; k0 < H_; k0 += 32) {
    bf16x8 a0 = *(const bf16x8*)(pa0 + k0);
    bf16x8 a1 = *(const bf16x8*)(pa1 + k0);
    bf16x8 b  = *(const bf16x8*)(pb + k0);
    acc0 = __builtin_amdgcn_mfma_f32_16x16x32_bf16(a0, b, acc0, 0, 0, 0);
    acc1 = __builtin_amdgcn_mfma_f32_16x16x32_bf16(a1, b, acc1, 0, 0, 0);
  }

  // K-part 2: input x_t @ W_ih^T  (K = 512, fp32 source, convert in-reg)
  const float* px0 = x + ((long)(r0 + lr) * T_ + t) * I_ + kg * 8;
  const float* px1 = px0 + (long)16 * T_ * I_;
  const ushort_t* pbx = pb + H_;
  #pragma unroll 4
  for (int k0 = 0; k0 < I_; k0 += 32) {
    bf16x8 a0 = cvt8(px0 + k0);
    bf16x8 a1 = cvt8(px1 + k0);
    bf16x8 b  = *(const bf16x8*)(pbx + k0);
    acc0 = __builtin_amdgcn_mfma_f32_16x16x32_bf16(a0, b, acc0, 0, 0, 0);
    acc1 = __builtin_amdgcn_mfma_f32_16x16x32_bf16(a1, b, acc1, 0, 0, 0);
  }

  // epilogue: +bias, relu, store bf16.  C/D layout: col = lane&15, row = kg*4 + reg
  const int col = c0 + lr;
  const float bias = bcat[col];
  const int rowb = r0 + kg * 4;
  #pragma unroll
  for (int r = 0; r < 4; ++r) {
    float v0 = acc0[r] + bias; v0 = v0 > 0.f ? v0 : 0.f;
    h_nxt[(rowb + r) * H_ + col] = f2bf(v0);
    float v1 = acc1[r] + bias; v1 = v1 > 0.f ? v1 : 0.f;
    h_nxt[(rowb + r + 16) * H_ + col] = f2bf(v1);
  }
}

// out = h_final @ W_ho^T + b_ho   (M=128, N=512, K=1024), fp32 output
__global__ __launch_bounds__(64) void k_out(const ushort_t* __restrict__ h,
                                            const ushort_t* __restrict__ Wob,
                                            const float* __restrict__ bho,
                                            float* __restrict__ out) {
  const int lane = threadIdx.x;
  const int lr = lane & 15;
  const int kg = lane >> 4;
  const int bm = blockIdx.x & 3;    // 4 row tiles of 32
  const int bn = blockIdx.x >> 2;   // 32 col tiles of 16
  const int r0 = bm * 32, c0 = bn * 16;

  const ushort_t* pa0 = h + (r0 + lr) * H_ + kg * 8;
  const ushort_t* pa1 = pa0 + 16 * H_;
  const ushort_t* pb  = Wob + (c0 + lr) * H_ + kg * 8;

  f32x4 acc0 = {0.f, 0.f, 0.f, 0.f};
  f32x4 acc1 = {0.f, 0.f, 0.f, 0.f};
  #pragma unroll 4
  for (int k0 = 0; k0 < H_; k0 += 32) {
    bf16x8 a0 = *(const bf16x8*)(pa0 + k0);
    bf16x8 a1 = *(const bf16x8*)(pa1 + k0);
    bf16x8 b  = *(const bf16x8*)(pb + k0);
    acc0 = __builtin_amdgcn_mfma_f32_16x16x32_bf16(a0, b, acc0, 0, 0, 0);
    acc1 = __builtin_amdgcn_mfma_f32_16x16x32_bf16(a1, b, acc1, 0, 0, 0);
  }

  const int col = c0 + lr;
  const float bias = bho[col];
  const int rowb = r0 + kg * 4;
  #pragma unroll
  for (int r = 0; r < 4; ++r) {
    out[(rowb + r) * O_ + col] = acc0[r] + bias;
    out[(rowb + r + 16) * O_ + col] = acc1[r] + bias;
  }
}

extern "C" void kernel_launch(void* const* d_in, const int* in_sizes, int n_in,
                              void* d_out, int out_size, void* d_ws, size_t ws_size,
                              hipStream_t stream) {
  const float* x   = (const float*)d_in[0];
  const float* Wih = (const float*)d_in[1];
  const float* bih = (const float*)d_in[2];
  const float* Whh = (const float*)d_in[3];
  const float* bhh = (const float*)d_in[4];
  const float* Who = (const float*)d_in[5];
  const float* bho = (const float*)d_in[6];
  float* out = (float*)d_out;

  char* ws = (char*)d_ws;
  ushort_t* Wcat = (ushort_t*)ws;                         // 1024*1536*2 = 3,145,728 B
  ushort_t* Wob  = (ushort_t*)(ws + 3145728);             // 512*1024*2  = 1,048,576 B
  float*    bcat = (float*)(ws + 3145728 + 1048576);      // 4096 B
  ushort_t* h0   = (ushort_t*)(ws + 4198400);             // 128*1024*2 = 262,144 B
  ushort_t* h1   = (ushort_t*)(ws + 4198400 + 262144);    // 262,144 B
  // total ~4.7 MB of ws

  hipLaunchKernelGGL(k_prep, dim3(1024), dim3(256), 0, stream,
                     Whh, Wih, Who, bih, bhh, Wcat, Wob, bcat, h0);

  ushort_t* hb[2] = {h0, h1};
  for (int t = 0; t < T_; ++t) {
    hipLaunchKernelGGL(k_step, dim3(256), dim3(64), 0, stream,
                       hb[t & 1], hb[(t + 1) & 1], x, Wcat, bcat, t);
  }
  // after 1024 steps, final h is in hb[0]
  hipLaunchKernelGGL(k_out, dim3(128), dim3(64), 0, stream, hb[0], Wob, bho, out);
}